// Round 1
// baseline (6037.255 us; speedup 1.0000x reference)
//
#include <hip/hip_runtime.h>
#include <cstdint>

#define D 128

// ---- degree count (atomic, once per launch) -------------------------------
__global__ __launch_bounds__(256) void deg_kernel(const int* __restrict__ src,
    const int* __restrict__ dst, float* __restrict__ deg_out,
    float* __restrict__ deg_in, int E) {
  int e = blockIdx.x * 256 + threadIdx.x;
  if (e < E) {
    atomicAdd(deg_out + src[e], 1.0f);
    atomicAdd(deg_in + dst[e], 1.0f);
  }
}

// ---- norm = rsqrt(max(deg,1)) in place ------------------------------------
__global__ __launch_bounds__(256) void norm_kernel(float* __restrict__ a,
    float* __restrict__ b, int N) {
  int i = blockIdx.x * 256 + threadIdx.x;
  if (i < N) {
    a[i] = rsqrtf(fmaxf(a[i], 1.0f));
    b[i] = rsqrtf(fmaxf(b[i], 1.0f));
  }
}

// ---- edge-parallel scatter: agg[dst] += x[src] * norm_src[src] ------------
// 32 threads per edge, each handles 4 contiguous floats (float4 gather).
__global__ __launch_bounds__(256) void scatter_kernel(const float* __restrict__ x,
    const float* __restrict__ norm_src, const int* __restrict__ src,
    const int* __restrict__ dst, float* __restrict__ agg, int E) {
  long long t = (long long)blockIdx.x * 256 + threadIdx.x;
  int e = (int)(t >> 5);
  if (e >= E) return;
  int g = (int)(t & 31);
  int s = src[e];
  int d = dst[e];
  float ns = norm_src[s];
  float4 v = ((const float4*)(x + (size_t)s * D))[g];
  float* ap = agg + (size_t)d * D + g * 4;
  atomicAdd(ap + 0, v.x * ns);
  atomicAdd(ap + 1, v.y * ns);
  atomicAdd(ap + 2, v.z * ns);
  atomicAdd(ap + 3, v.w * ns);
}

// ---- per-layer: x_out = leakyrelu((agg*norm_dst) @ W + b); jk = max(jk, x_out)
// W (64 KB fp32) staged in LDS once per block; block computes 64 rows.
// Threads: 32 col-groups (4 cols each) x 8 row-slots = 256.
__global__ __launch_bounds__(256) void layer_kernel(const float* __restrict__ agg,
    const float* __restrict__ norm_dst, const float* __restrict__ W,
    const float* __restrict__ bias, float* __restrict__ x_out,
    float* __restrict__ jk, int N) {
  __shared__ float Wl[D * D];
  __shared__ float arow[8][D];
  const float4* W4 = (const float4*)W;
  float4* Wl4 = (float4*)Wl;
  for (int i = threadIdx.x; i < D * D / 4; i += 256) Wl4[i] = W4[i];
  int cg = threadIdx.x & 31;
  int r = threadIdx.x >> 5;
  float4 bv = ((const float4*)bias)[cg];
  int row_base = blockIdx.x * 64;
  __syncthreads();
  for (int it = 0; it < 8; ++it) {
    int row = row_base + it * 8 + r;
    if (it) __syncthreads();
    if (row < N) {
      float nd = norm_dst[row];
      float4 a = ((const float4*)(agg + (size_t)row * D))[cg];
      a.x *= nd; a.y *= nd; a.z *= nd; a.w *= nd;
      ((float4*)arow[r])[cg] = a;
    }
    __syncthreads();
    if (row < N) {
      float4 acc = bv;
      #pragma unroll 16
      for (int k = 0; k < D; ++k) {
        float a = arow[r][k];
        float4 w = Wl4[k * 32 + cg];
        acc.x += a * w.x;
        acc.y += a * w.y;
        acc.z += a * w.z;
        acc.w += a * w.w;
      }
      acc.x = acc.x > 0.f ? acc.x : 0.01f * acc.x;
      acc.y = acc.y > 0.f ? acc.y : 0.01f * acc.y;
      acc.z = acc.z > 0.f ? acc.z : 0.01f * acc.z;
      acc.w = acc.w > 0.f ? acc.w : 0.01f * acc.w;
      size_t o4 = (size_t)row * 32 + cg;
      ((float4*)x_out)[o4] = acc;
      float4 m = ((float4*)jk)[o4];
      m.x = fmaxf(m.x, acc.x);
      m.y = fmaxf(m.y, acc.y);
      m.z = fmaxf(m.z, acc.z);
      m.w = fmaxf(m.w, acc.w);
      ((float4*)jk)[o4] = m;
    }
  }
}

extern "C" void kernel_launch(void* const* d_in, const int* in_sizes, int n_in,
                              void* d_out, int out_size, void* d_ws, size_t ws_size,
                              hipStream_t stream) {
  const float* in_feat = (const float*)d_in[0];
  const float* Ws = (const float*)d_in[1];
  const float* bs = (const float*)d_in[2];
  const int* src = (const int*)d_in[3];
  const int* dst = (const int*)d_in[4];
  int N = in_sizes[0] / D;
  int L = in_sizes[2] / D;
  int E = in_sizes[3];
  float* out = (float*)d_out;

  size_t Npad = (size_t)((N + 63) & ~63);
  float* norm_src = (float*)d_ws;
  float* norm_dst = norm_src + Npad;
  float* x = norm_dst + Npad;
  float* agg = x + Npad * D;

  // degrees -> norms (fresh every launch; deterministic)
  hipMemsetAsync(norm_src, 0, 2 * Npad * sizeof(float), stream);
  deg_kernel<<<(E + 255) / 256, 256, 0, stream>>>(src, dst, norm_src, norm_dst, E);
  norm_kernel<<<(N + 255) / 256, 256, 0, stream>>>(norm_src, norm_dst, N);

  // JK running max seeded with in_feat
  hipMemcpyAsync(out, in_feat, (size_t)N * D * sizeof(float),
                 hipMemcpyDeviceToDevice, stream);

  long long sthreads = (long long)E * 32;
  int sblocks = (int)((sthreads + 255) / 256);
  int gblocks = (N + 63) / 64;
  for (int l = 0; l < L; ++l) {
    hipMemsetAsync(agg, 0, (size_t)N * D * sizeof(float), stream);
    scatter_kernel<<<sblocks, 256, 0, stream>>>(l == 0 ? in_feat : x, norm_src,
                                                src, dst, agg, E);
    layer_kernel<<<gblocks, 256, 0, stream>>>(agg, norm_dst, Ws + (size_t)l * D * D,
                                              bs + (size_t)l * D, x, out, N);
  }
}

// Round 3
// 931.106 us; speedup vs baseline: 6.4840x; 6.4840x over previous
//
#include <hip/hip_runtime.h>
#include <cstdint>

#define D 128

// ---- integer degree count --------------------------------------------------
__global__ __launch_bounds__(256) void deg_kernel(const int* __restrict__ src,
    const int* __restrict__ dst, int* __restrict__ dego, int* __restrict__ degi,
    int E) {
  int e = blockIdx.x * 256 + threadIdx.x;
  if (e < E) {
    atomicAdd(dego + src[e], 1);
    atomicAdd(degi + dst[e], 1);
  }
}

// ---- norms from int degrees -------------------------------------------------
__global__ __launch_bounds__(256) void norm_kernel(const int* __restrict__ dego,
    const int* __restrict__ degi, float* __restrict__ ns, float* __restrict__ nd,
    int N) {
  int i = blockIdx.x * 256 + threadIdx.x;
  if (i < N) {
    ns[i] = rsqrtf(fmaxf((float)dego[i], 1.0f));
    nd[i] = rsqrtf(fmaxf((float)degi[i], 1.0f));
  }
}

// ---- single-block exclusive scan over in-degrees -> row_ptr[N+1] + cursor ---
__global__ __launch_bounds__(1024) void scan_kernel(const int* __restrict__ deg,
    int* __restrict__ row_ptr, int* __restrict__ cursor, int N, int E) {
  __shared__ int sums[1024];
  int t = threadIdx.x;
  int chunk = (N + 1023) / 1024;
  int b = t * chunk;
  int e = min(b + chunk, N);
  int s = 0;
  for (int i = b; i < e; ++i) s += deg[i];
  sums[t] = s;
  __syncthreads();
  for (int off = 1; off < 1024; off <<= 1) {
    int v = (t >= off) ? sums[t - off] : 0;
    __syncthreads();
    sums[t] += v;
    __syncthreads();
  }
  int run = (t == 0) ? 0 : sums[t - 1];
  for (int i = b; i < e; ++i) {
    row_ptr[i] = run;
    cursor[i] = run;
    run += deg[i];
  }
  if (t == 1023) row_ptr[N] = E;
}

// ---- scatter edges into CSR slots (order within a row is irrelevant) --------
__global__ __launch_bounds__(256) void fill_csr(const int* __restrict__ src,
    const int* __restrict__ dst, int* __restrict__ cursor, int* __restrict__ esrc,
    int E) {
  int e = blockIdx.x * 256 + threadIdx.x;
  if (e < E) {
    int slot = atomicAdd(cursor + dst[e], 1);
    esrc[slot] = src[e];
  }
}

// ---- fused: CSR gather -> GEMM(W in LDS) -> bias -> LeakyReLU -> JK max -----
// 256 threads = 8 row-slots x 32 col-groups (4 cols each); block covers 64 rows.
// xin and xout MUST be distinct allocations (cross-block gather hazard).
__global__ __launch_bounds__(256) void layer_fused(const float* __restrict__ xin,
    const int* __restrict__ row_ptr, const int* __restrict__ esrc,
    const float* __restrict__ norm_src, const float* __restrict__ norm_dst,
    const float* __restrict__ W, const float* __restrict__ bias,
    float* __restrict__ xout, float* __restrict__ jk, int N) {
  __shared__ float Wl[D * D];       // 64 KB
  __shared__ float arow[8][D];      // 4 KB
  const float4* W4 = (const float4*)W;
  float4* Wl4 = (float4*)Wl;
  for (int i = threadIdx.x; i < D * D / 4; i += 256) Wl4[i] = W4[i];
  int cg = threadIdx.x & 31;
  int slot = threadIdx.x >> 5;
  float4 bv = ((const float4*)bias)[cg];
  int row_base = blockIdx.x * 64;
  __syncthreads();
  for (int it = 0; it < 8; ++it) {
    int row = row_base + it * 8 + slot;
    if (it) __syncthreads();  // arow reuse guard
    if (row < N) {
      float4 acc = {0.f, 0.f, 0.f, 0.f};
      int b = row_ptr[row];
      int e = row_ptr[row + 1];
      int j = b;
      for (; j + 1 < e; j += 2) {   // 2x unroll for load ILP
        int s0 = esrc[j];
        int s1 = esrc[j + 1];
        float n0 = norm_src[s0];
        float n1 = norm_src[s1];
        float4 v0 = ((const float4*)(xin + (size_t)s0 * D))[cg];
        float4 v1 = ((const float4*)(xin + (size_t)s1 * D))[cg];
        acc.x += v0.x * n0; acc.y += v0.y * n0;
        acc.z += v0.z * n0; acc.w += v0.w * n0;
        acc.x += v1.x * n1; acc.y += v1.y * n1;
        acc.z += v1.z * n1; acc.w += v1.w * n1;
      }
      if (j < e) {
        int s0 = esrc[j];
        float n0 = norm_src[s0];
        float4 v0 = ((const float4*)(xin + (size_t)s0 * D))[cg];
        acc.x += v0.x * n0; acc.y += v0.y * n0;
        acc.z += v0.z * n0; acc.w += v0.w * n0;
      }
      float nd = norm_dst[row];
      acc.x *= nd; acc.y *= nd; acc.z *= nd; acc.w *= nd;
      ((float4*)arow[slot])[cg] = acc;
    }
    __syncthreads();
    if (row < N) {
      float4 o = bv;
      #pragma unroll 16
      for (int k = 0; k < D; ++k) {
        float a = arow[slot][k];
        float4 w = Wl4[k * 32 + cg];
        o.x += a * w.x; o.y += a * w.y; o.z += a * w.z; o.w += a * w.w;
      }
      o.x = o.x > 0.f ? o.x : 0.01f * o.x;
      o.y = o.y > 0.f ? o.y : 0.01f * o.y;
      o.z = o.z > 0.f ? o.z : 0.01f * o.z;
      o.w = o.w > 0.f ? o.w : 0.01f * o.w;
      size_t o4 = (size_t)row * 32 + cg;
      ((float4*)xout)[o4] = o;
      float4 m = ((float4*)jk)[o4];
      m.x = fmaxf(m.x, o.x); m.y = fmaxf(m.y, o.y);
      m.z = fmaxf(m.z, o.z); m.w = fmaxf(m.w, o.w);
      ((float4*)jk)[o4] = m;
    }
  }
}

extern "C" void kernel_launch(void* const* d_in, const int* in_sizes, int n_in,
                              void* d_out, int out_size, void* d_ws, size_t ws_size,
                              hipStream_t stream) {
  const float* in_feat = (const float*)d_in[0];
  const float* Ws = (const float*)d_in[1];
  const float* bs = (const float*)d_in[2];
  const int* src = (const int*)d_in[3];
  const int* dst = (const int*)d_in[4];
  int N = in_sizes[0] / D;
  int L = in_sizes[2] / D;
  int E = in_sizes[3];
  float* out = (float*)d_out;

  // workspace layout (ints and floats both 4 B)
  char* p = (char*)d_ws;
  int* dego    = (int*)p;            p += (size_t)N * 4;   // reused as CSR cursor
  int* degi    = (int*)p;            p += (size_t)N * 4;
  int* row_ptr = (int*)p;            p += (size_t)(N + 1) * 4;
  int* esrc    = (int*)p;            p += (size_t)E * 4;
  float* nsrc  = (float*)p;          p += (size_t)N * 4;
  float* ndst  = (float*)p;          p += (size_t)N * 4;
  float* x0    = (float*)p;          p += (size_t)N * D * 4;
  float* x1    = (float*)p;          // N*D floats

  hipMemsetAsync(dego, 0, 2 * (size_t)N * 4, stream);  // dego+degi contiguous
  deg_kernel<<<(E + 255) / 256, 256, 0, stream>>>(src, dst, dego, degi, E);
  norm_kernel<<<(N + 255) / 256, 256, 0, stream>>>(dego, degi, nsrc, ndst, N);
  // norms consumed dego -> reuse it as the CSR fill cursor
  scan_kernel<<<1, 1024, 0, stream>>>(degi, row_ptr, dego, N, E);
  fill_csr<<<(E + 255) / 256, 256, 0, stream>>>(src, dst, dego, esrc, E);

  // seed JK running max with in_feat
  hipMemcpyAsync(out, in_feat, (size_t)N * D * 4, hipMemcpyDeviceToDevice, stream);

  int gblocks = (N + 63) / 64;
  float* bufs[2] = {x0, x1};
  for (int l = 0; l < L; ++l) {
    const float* xin = (l == 0) ? in_feat : bufs[(l - 1) & 1];
    float* xout = bufs[l & 1];
    layer_fused<<<gblocks, 256, 0, stream>>>(xin, row_ptr, esrc, nsrc, ndst,
                                             Ws + (size_t)l * D * D,
                                             bs + (size_t)l * D, xout, out, N);
  }
}

// Round 5
// 688.506 us; speedup vs baseline: 8.7686x; 1.3524x over previous
//
#include <hip/hip_runtime.h>
#include <cstdint>

#define D 128
#define RPB 32   // rows per gemm block

// ---- integer degree count --------------------------------------------------
__global__ __launch_bounds__(256) void deg_kernel(const int* __restrict__ src,
    const int* __restrict__ dst, int* __restrict__ dego, int* __restrict__ degi,
    int E) {
  int e = blockIdx.x * 256 + threadIdx.x;
  if (e < E) {
    atomicAdd(dego + src[e], 1);
    atomicAdd(degi + dst[e], 1);
  }
}

// ---- norms from int degrees -------------------------------------------------
__global__ __launch_bounds__(256) void norm_kernel(const int* __restrict__ dego,
    const int* __restrict__ degi, float* __restrict__ ns, float* __restrict__ nd,
    int N) {
  int i = blockIdx.x * 256 + threadIdx.x;
  if (i < N) {
    ns[i] = rsqrtf(fmaxf((float)dego[i], 1.0f));
    nd[i] = rsqrtf(fmaxf((float)degi[i], 1.0f));
  }
}

// ---- single-block exclusive scan over in-degrees -> row_ptr[N+1] + cursor ---
__global__ __launch_bounds__(1024) void scan_kernel(const int* __restrict__ deg,
    int* __restrict__ row_ptr, int* __restrict__ cursor, int N, int E) {
  __shared__ int sums[1024];
  int t = threadIdx.x;
  int chunk = (N + 1023) / 1024;
  int b = t * chunk;
  int e = min(b + chunk, N);
  int s = 0;
  for (int i = b; i < e; ++i) s += deg[i];
  sums[t] = s;
  __syncthreads();
  for (int off = 1; off < 1024; off <<= 1) {
    int v = (t >= off) ? sums[t - off] : 0;
    __syncthreads();
    sums[t] += v;
    __syncthreads();
  }
  int run = (t == 0) ? 0 : sums[t - 1];
  for (int i = b; i < e; ++i) {
    row_ptr[i] = run;
    cursor[i] = run;
    run += deg[i];
  }
  if (t == 1023) row_ptr[N] = E;
}

// ---- scatter edges into CSR slots (order within a row is irrelevant) --------
__global__ __launch_bounds__(256) void fill_csr(const int* __restrict__ src,
    const int* __restrict__ dst, int* __restrict__ cursor, int* __restrict__ esrc,
    int E) {
  int e = blockIdx.x * 256 + threadIdx.x;
  if (e < E) {
    int slot = atomicAdd(cursor + dst[e], 1);
    esrc[slot] = src[e];
  }
}

// ---- high-occupancy CSR gather: agg[row] = ndst[row] * sum nsrc[s]*x[s] -----
// 32 lanes per row (float4 each), no LDS, 4x unrolled edge loop.
__global__ __launch_bounds__(256, 8) void gather_kernel(const float* __restrict__ xin,
    const int* __restrict__ row_ptr, const int* __restrict__ esrc,
    const float* __restrict__ nsrc, const float* __restrict__ ndst,
    float* __restrict__ agg, int N) {
  int t = blockIdx.x * 256 + threadIdx.x;
  int row = t >> 5;
  if (row >= N) return;
  int cg = t & 31;
  int b = row_ptr[row];
  int e = row_ptr[row + 1];
  float4 acc = {0.f, 0.f, 0.f, 0.f};
  int j = b;
  for (; j + 3 < e; j += 4) {
    int s0 = esrc[j];
    int s1 = esrc[j + 1];
    int s2 = esrc[j + 2];
    int s3 = esrc[j + 3];
    float4 v0 = ((const float4*)(xin + (size_t)s0 * D))[cg];
    float4 v1 = ((const float4*)(xin + (size_t)s1 * D))[cg];
    float4 v2 = ((const float4*)(xin + (size_t)s2 * D))[cg];
    float4 v3 = ((const float4*)(xin + (size_t)s3 * D))[cg];
    float n0 = nsrc[s0];
    float n1 = nsrc[s1];
    float n2 = nsrc[s2];
    float n3 = nsrc[s3];
    acc.x += v0.x * n0; acc.y += v0.y * n0; acc.z += v0.z * n0; acc.w += v0.w * n0;
    acc.x += v1.x * n1; acc.y += v1.y * n1; acc.z += v1.z * n1; acc.w += v1.w * n1;
    acc.x += v2.x * n2; acc.y += v2.y * n2; acc.z += v2.z * n2; acc.w += v2.w * n2;
    acc.x += v3.x * n3; acc.y += v3.y * n3; acc.z += v3.z * n3; acc.w += v3.w * n3;
  }
  for (; j < e; ++j) {
    int s0 = esrc[j];
    float n0 = nsrc[s0];
    float4 v0 = ((const float4*)(xin + (size_t)s0 * D))[cg];
    acc.x += v0.x * n0; acc.y += v0.y * n0; acc.z += v0.z * n0; acc.w += v0.w * n0;
  }
  float nd = ndst[row];
  acc.x *= nd; acc.y *= nd; acc.z *= nd; acc.w *= nd;
  ((float4*)(agg + (size_t)row * D))[cg] = acc;
}

// ---- register-blocked GEMM: x_out = leakyrelu(agg @ W + b); jk max fused ----
// 256 threads = 32 col-groups x 8 slots; slot owns 4 rows; block covers 32 rows.
// LDS: W 64KB + A-tile 16KB = 80KB -> 2 blocks/CU.
__device__ __forceinline__ void fma4(float4& acc, float a, const float4& wv) {
  acc.x += a * wv.x;
  acc.y += a * wv.y;
  acc.z += a * wv.z;
  acc.w += a * wv.w;
}

__global__ __launch_bounds__(256, 2) void gemm_kernel(const float* __restrict__ agg,
    const float* __restrict__ W, const float* __restrict__ bias,
    const float* __restrict__ jk_in, float* __restrict__ xout,
    float* __restrict__ jk_out, int N) {
  __shared__ float Wl[D * D];       // 64 KB
  __shared__ float Al[RPB * D];     // 16 KB
  float4* Wl4 = (float4*)Wl;
  float4* Al4 = (float4*)Al;
  const float4* W4 = (const float4*)W;
  for (int i = threadIdx.x; i < D * D / 4; i += 256) Wl4[i] = W4[i];
  int row0 = blockIdx.x * RPB;
  for (int i = threadIdx.x; i < RPB * D / 4; i += 256) {
    int r = i >> 5;
    int row = row0 + r;
    float4 z = {0.f, 0.f, 0.f, 0.f};
    Al4[i] = (row < N) ? ((const float4*)(agg + (size_t)row * D))[i & 31] : z;
  }
  __syncthreads();

  int cg = threadIdx.x & 31;
  int slot = threadIdx.x >> 5;          // rows slot*4 .. slot*4+3
  float4 bv = ((const float4*)bias)[cg];
  float4 acc0 = bv, acc1 = bv, acc2 = bv, acc3 = bv;
  int abase = slot * 4 * 32;            // float4 index of row slot*4

  #pragma unroll 8
  for (int k = 0; k < D; k += 4) {
    float4 w0 = Wl4[(k + 0) * 32 + cg];
    float4 w1 = Wl4[(k + 1) * 32 + cg];
    float4 w2 = Wl4[(k + 2) * 32 + cg];
    float4 w3 = Wl4[(k + 3) * 32 + cg];
    int k4 = k >> 2;
    float4 a0 = Al4[abase + k4];
    float4 a1 = Al4[abase + 32 + k4];
    float4 a2 = Al4[abase + 64 + k4];
    float4 a3 = Al4[abase + 96 + k4];
    fma4(acc0, a0.x, w0); fma4(acc0, a0.y, w1); fma4(acc0, a0.z, w2); fma4(acc0, a0.w, w3);
    fma4(acc1, a1.x, w0); fma4(acc1, a1.y, w1); fma4(acc1, a1.z, w2); fma4(acc1, a1.w, w3);
    fma4(acc2, a2.x, w0); fma4(acc2, a2.y, w1); fma4(acc2, a2.z, w2); fma4(acc2, a2.w, w3);
    fma4(acc3, a3.x, w0); fma4(acc3, a3.y, w1); fma4(acc3, a3.z, w2); fma4(acc3, a3.w, w3);
  }

  #pragma unroll
  for (int q = 0; q < 4; ++q) {
    float4 o = (q == 0) ? acc0 : (q == 1) ? acc1 : (q == 2) ? acc2 : acc3;
    int row = row0 + slot * 4 + q;
    if (row < N) {
      o.x = o.x > 0.f ? o.x : 0.01f * o.x;
      o.y = o.y > 0.f ? o.y : 0.01f * o.y;
      o.z = o.z > 0.f ? o.z : 0.01f * o.z;
      o.w = o.w > 0.f ? o.w : 0.01f * o.w;
      size_t o4 = (size_t)row * 32 + cg;
      ((float4*)xout)[o4] = o;
      float4 m = ((const float4*)jk_in)[o4];
      m.x = fmaxf(m.x, o.x); m.y = fmaxf(m.y, o.y);
      m.z = fmaxf(m.z, o.z); m.w = fmaxf(m.w, o.w);
      ((float4*)jk_out)[o4] = m;
    }
  }
}

extern "C" void kernel_launch(void* const* d_in, const int* in_sizes, int n_in,
                              void* d_out, int out_size, void* d_ws, size_t ws_size,
                              hipStream_t stream) {
  const float* in_feat = (const float*)d_in[0];
  const float* Ws = (const float*)d_in[1];
  const float* bs = (const float*)d_in[2];
  const int* src = (const int*)d_in[3];
  const int* dst = (const int*)d_in[4];
  int N = in_sizes[0] / D;
  int L = in_sizes[2] / D;
  int E = in_sizes[3];
  float* out = (float*)d_out;

  // workspace layout
  char* p = (char*)d_ws;
  int* dego    = (int*)p;   p += (size_t)N * 4;      // reused as CSR cursor
  int* degi    = (int*)p;   p += (size_t)N * 4;
  int* row_ptr = (int*)p;   p += (size_t)(N + 1) * 4;
  int* esrc    = (int*)p;   p += (size_t)E * 4;
  float* nsrc  = (float*)p; p += (size_t)N * 4;
  float* ndst  = (float*)p; p += (size_t)N * 4;
  float* agg   = (float*)p; p += (size_t)N * D * 4;
  float* x     = (float*)p;                           // N*D floats

  hipMemsetAsync(dego, 0, 2 * (size_t)N * 4, stream);
  deg_kernel<<<(E + 255) / 256, 256, 0, stream>>>(src, dst, dego, degi, E);
  norm_kernel<<<(N + 255) / 256, 256, 0, stream>>>(dego, degi, nsrc, ndst, N);
  scan_kernel<<<1, 1024, 0, stream>>>(degi, row_ptr, dego, N, E);
  fill_csr<<<(E + 255) / 256, 256, 0, stream>>>(src, dst, dego, esrc, E);

  int gb = (int)(((long long)N * 32 + 255) / 256);
  int mb = (N + RPB - 1) / RPB;
  for (int l = 0; l < L; ++l) {
    const float* xin = (l == 0) ? in_feat : x;
    const float* jk_in = (l == 0) ? in_feat : out;   // layer 0 seeds JK max
    gather_kernel<<<gb, 256, 0, stream>>>(xin, row_ptr, esrc, nsrc, ndst, agg, N);
    gemm_kernel<<<mb, 256, 0, stream>>>(agg, Ws + (size_t)l * D * D,
                                        bs + (size_t)l * D, jk_in, x, out, N);
  }
}

// Round 6
// 588.197 us; speedup vs baseline: 10.2640x; 1.1705x over previous
//
#include <hip/hip_runtime.h>
#include <cstdint>

#define D 128
#define RPB 32   // rows per gemm block

// ---- integer degree count --------------------------------------------------
__global__ __launch_bounds__(256) void deg_kernel(const int* __restrict__ src,
    const int* __restrict__ dst, int* __restrict__ dego, int* __restrict__ degi,
    int E) {
  int e = blockIdx.x * 256 + threadIdx.x;
  if (e < E) {
    atomicAdd(dego + src[e], 1);
    atomicAdd(degi + dst[e], 1);
  }
}

// ---- norms from int degrees -------------------------------------------------
__global__ __launch_bounds__(256) void norm_kernel(const int* __restrict__ dego,
    const int* __restrict__ degi, float* __restrict__ ns, float* __restrict__ nd,
    int N) {
  int i = blockIdx.x * 256 + threadIdx.x;
  if (i < N) {
    ns[i] = rsqrtf(fmaxf((float)dego[i], 1.0f));
    nd[i] = rsqrtf(fmaxf((float)degi[i], 1.0f));
  }
}

// ---- hierarchical exclusive scan (3 stages, all wide) -----------------------
// scan1: per-block exclusive scan of deg; local result -> loc, block total -> bsum
__global__ __launch_bounds__(256) void scan1_kernel(const int* __restrict__ deg,
    int* __restrict__ loc, int* __restrict__ bsum, int N) {
  __shared__ int tmp[256];
  int i = blockIdx.x * 256 + threadIdx.x;
  int v = (i < N) ? deg[i] : 0;
  tmp[threadIdx.x] = v;
  __syncthreads();
  #pragma unroll
  for (int off = 1; off < 256; off <<= 1) {
    int t = (threadIdx.x >= off) ? tmp[threadIdx.x - off] : 0;
    __syncthreads();
    tmp[threadIdx.x] += t;
    __syncthreads();
  }
  if (i < N) loc[i] = tmp[threadIdx.x] - v;      // exclusive
  if (threadIdx.x == 255) bsum[blockIdx.x] = tmp[255];
}

// scan2: single small block scans the block totals (nb <= 256) into exclusive offsets
__global__ __launch_bounds__(256) void scan2_kernel(int* __restrict__ bsum, int nb) {
  __shared__ int tmp[256];
  int t = threadIdx.x;
  int v = (t < nb) ? bsum[t] : 0;
  tmp[t] = v;
  __syncthreads();
  #pragma unroll
  for (int off = 1; off < 256; off <<= 1) {
    int u = (t >= off) ? tmp[t - off] : 0;
    __syncthreads();
    tmp[t] += u;
    __syncthreads();
  }
  if (t < nb) bsum[t] = tmp[t] - v;              // exclusive block offset
}

// scan3: row_ptr[i] = loc[i] + bsum[blk]; duplicate into cursor; cap row_ptr[N]
__global__ __launch_bounds__(256) void scan3_kernel(const int* __restrict__ loc,
    const int* __restrict__ bsum, int* __restrict__ row_ptr,
    int* __restrict__ cursor, int N, int E) {
  int i = blockIdx.x * 256 + threadIdx.x;
  if (i < N) {
    int v = loc[i] + bsum[blockIdx.x];
    row_ptr[i] = v;
    cursor[i] = v;
  }
  if (i == 0) row_ptr[N] = E;
}

// ---- scatter edges into CSR slots (order within a row is irrelevant) --------
__global__ __launch_bounds__(256) void fill_csr(const int* __restrict__ src,
    const int* __restrict__ dst, int* __restrict__ cursor, int* __restrict__ esrc,
    int E) {
  int e = blockIdx.x * 256 + threadIdx.x;
  if (e < E) {
    int slot = atomicAdd(cursor + dst[e], 1);
    esrc[slot] = src[e];
  }
}

// ---- high-occupancy CSR gather: agg[row] = ndst[row] * sum nsrc[s]*x[s] -----
// 32 lanes per row (float4 each), no LDS, 4x unrolled edge loop.
__global__ __launch_bounds__(256, 8) void gather_kernel(const float* __restrict__ xin,
    const int* __restrict__ row_ptr, const int* __restrict__ esrc,
    const float* __restrict__ nsrc, const float* __restrict__ ndst,
    float* __restrict__ agg, int N) {
  int t = blockIdx.x * 256 + threadIdx.x;
  int row = t >> 5;
  if (row >= N) return;
  int cg = t & 31;
  int b = row_ptr[row];
  int e = row_ptr[row + 1];
  float4 acc = {0.f, 0.f, 0.f, 0.f};
  int j = b;
  for (; j + 3 < e; j += 4) {
    int s0 = esrc[j];
    int s1 = esrc[j + 1];
    int s2 = esrc[j + 2];
    int s3 = esrc[j + 3];
    float4 v0 = ((const float4*)(xin + (size_t)s0 * D))[cg];
    float4 v1 = ((const float4*)(xin + (size_t)s1 * D))[cg];
    float4 v2 = ((const float4*)(xin + (size_t)s2 * D))[cg];
    float4 v3 = ((const float4*)(xin + (size_t)s3 * D))[cg];
    float n0 = nsrc[s0];
    float n1 = nsrc[s1];
    float n2 = nsrc[s2];
    float n3 = nsrc[s3];
    acc.x += v0.x * n0; acc.y += v0.y * n0; acc.z += v0.z * n0; acc.w += v0.w * n0;
    acc.x += v1.x * n1; acc.y += v1.y * n1; acc.z += v1.z * n1; acc.w += v1.w * n1;
    acc.x += v2.x * n2; acc.y += v2.y * n2; acc.z += v2.z * n2; acc.w += v2.w * n2;
    acc.x += v3.x * n3; acc.y += v3.y * n3; acc.z += v3.z * n3; acc.w += v3.w * n3;
  }
  for (; j < e; ++j) {
    int s0 = esrc[j];
    float n0 = nsrc[s0];
    float4 v0 = ((const float4*)(xin + (size_t)s0 * D))[cg];
    acc.x += v0.x * n0; acc.y += v0.y * n0; acc.z += v0.z * n0; acc.w += v0.w * n0;
  }
  float nd = ndst[row];
  acc.x *= nd; acc.y *= nd; acc.z *= nd; acc.w *= nd;
  ((float4*)(agg + (size_t)row * D))[cg] = acc;
}

// ---- register-blocked GEMM: x_out = leakyrelu(agg @ W + b); jk max fused ----
__device__ __forceinline__ void fma4(float4& acc, float a, const float4& wv) {
  acc.x += a * wv.x;
  acc.y += a * wv.y;
  acc.z += a * wv.z;
  acc.w += a * wv.w;
}

__global__ __launch_bounds__(256, 2) void gemm_kernel(const float* __restrict__ agg,
    const float* __restrict__ W, const float* __restrict__ bias,
    const float* __restrict__ jk_in, float* __restrict__ xout,
    float* __restrict__ jk_out, int N) {
  __shared__ float Wl[D * D];       // 64 KB
  __shared__ float Al[RPB * D];     // 16 KB
  float4* Wl4 = (float4*)Wl;
  float4* Al4 = (float4*)Al;
  const float4* W4 = (const float4*)W;
  for (int i = threadIdx.x; i < D * D / 4; i += 256) Wl4[i] = W4[i];
  int row0 = blockIdx.x * RPB;
  for (int i = threadIdx.x; i < RPB * D / 4; i += 256) {
    int r = i >> 5;
    int row = row0 + r;
    float4 z = {0.f, 0.f, 0.f, 0.f};
    Al4[i] = (row < N) ? ((const float4*)(agg + (size_t)row * D))[i & 31] : z;
  }
  __syncthreads();

  int cg = threadIdx.x & 31;
  int slot = threadIdx.x >> 5;          // rows slot*4 .. slot*4+3
  float4 bv = ((const float4*)bias)[cg];
  float4 acc0 = bv, acc1 = bv, acc2 = bv, acc3 = bv;
  int abase = slot * 4 * 32;            // float4 index of row slot*4

  #pragma unroll 8
  for (int k = 0; k < D; k += 4) {
    float4 w0 = Wl4[(k + 0) * 32 + cg];
    float4 w1 = Wl4[(k + 1) * 32 + cg];
    float4 w2 = Wl4[(k + 2) * 32 + cg];
    float4 w3 = Wl4[(k + 3) * 32 + cg];
    int k4 = k >> 2;
    float4 a0 = Al4[abase + k4];
    float4 a1 = Al4[abase + 32 + k4];
    float4 a2 = Al4[abase + 64 + k4];
    float4 a3 = Al4[abase + 96 + k4];
    fma4(acc0, a0.x, w0); fma4(acc0, a0.y, w1); fma4(acc0, a0.z, w2); fma4(acc0, a0.w, w3);
    fma4(acc1, a1.x, w0); fma4(acc1, a1.y, w1); fma4(acc1, a1.z, w2); fma4(acc1, a1.w, w3);
    fma4(acc2, a2.x, w0); fma4(acc2, a2.y, w1); fma4(acc2, a2.z, w2); fma4(acc2, a2.w, w3);
    fma4(acc3, a3.x, w0); fma4(acc3, a3.y, w1); fma4(acc3, a3.z, w2); fma4(acc3, a3.w, w3);
  }

  #pragma unroll
  for (int q = 0; q < 4; ++q) {
    float4 o = (q == 0) ? acc0 : (q == 1) ? acc1 : (q == 2) ? acc2 : acc3;
    int row = row0 + slot * 4 + q;
    if (row < N) {
      o.x = o.x > 0.f ? o.x : 0.01f * o.x;
      o.y = o.y > 0.f ? o.y : 0.01f * o.y;
      o.z = o.z > 0.f ? o.z : 0.01f * o.z;
      o.w = o.w > 0.f ? o.w : 0.01f * o.w;
      size_t o4 = (size_t)row * 32 + cg;
      ((float4*)xout)[o4] = o;
      float4 m = ((const float4*)jk_in)[o4];
      m.x = fmaxf(m.x, o.x); m.y = fmaxf(m.y, o.y);
      m.z = fmaxf(m.z, o.z); m.w = fmaxf(m.w, o.w);
      ((float4*)jk_out)[o4] = m;
    }
  }
}

extern "C" void kernel_launch(void* const* d_in, const int* in_sizes, int n_in,
                              void* d_out, int out_size, void* d_ws, size_t ws_size,
                              hipStream_t stream) {
  const float* in_feat = (const float*)d_in[0];
  const float* Ws = (const float*)d_in[1];
  const float* bs = (const float*)d_in[2];
  const int* src = (const int*)d_in[3];
  const int* dst = (const int*)d_in[4];
  int N = in_sizes[0] / D;
  int L = in_sizes[2] / D;
  int E = in_sizes[3];
  float* out = (float*)d_out;

  int nb = (N + 255) / 256;   // scan blocks (196 for N=50000, must be <= 256)

  // workspace layout
  char* p = (char*)d_ws;
  int* dego    = (int*)p;   p += (size_t)N * 4;      // later: local-scan temp
  int* degi    = (int*)p;   p += (size_t)N * 4;
  int* row_ptr = (int*)p;   p += (size_t)(N + 1) * 4;
  int* cursor  = (int*)p;   p += (size_t)N * 4;
  int* bsum    = (int*)p;   p += 256 * 4;
  int* esrc    = (int*)p;   p += (size_t)E * 4;
  float* nsrc  = (float*)p; p += (size_t)N * 4;
  float* ndst  = (float*)p; p += (size_t)N * 4;
  float* agg   = (float*)p; p += (size_t)N * D * 4;
  float* x     = (float*)p;                           // N*D floats

  hipMemsetAsync(dego, 0, 2 * (size_t)N * 4, stream);
  deg_kernel<<<(E + 255) / 256, 256, 0, stream>>>(src, dst, dego, degi, E);
  norm_kernel<<<(N + 255) / 256, 256, 0, stream>>>(dego, degi, nsrc, ndst, N);
  // hierarchical scan of degi -> row_ptr (+cursor); dego reused as local temp
  scan1_kernel<<<nb, 256, 0, stream>>>(degi, dego, bsum, N);
  scan2_kernel<<<1, 256, 0, stream>>>(bsum, nb);
  scan3_kernel<<<nb, 256, 0, stream>>>(dego, bsum, row_ptr, cursor, N, E);
  fill_csr<<<(E + 255) / 256, 256, 0, stream>>>(src, dst, cursor, esrc, E);

  int gb = (int)(((long long)N * 32 + 255) / 256);
  int mb = (N + RPB - 1) / RPB;
  for (int l = 0; l < L; ++l) {
    const float* xin = (l == 0) ? in_feat : x;
    const float* jk_in = (l == 0) ? in_feat : out;   // layer 0 seeds JK max
    gather_kernel<<<gb, 256, 0, stream>>>(xin, row_ptr, esrc, nsrc, ndst, agg, N);
    gemm_kernel<<<mb, 256, 0, stream>>>(agg, Ws + (size_t)l * D * D,
                                        bs + (size_t)l * D, jk_in, x, out, N);
  }
}

// Round 7
// 491.421 us; speedup vs baseline: 12.2853x; 1.1969x over previous
//
#include <hip/hip_runtime.h>
#include <cstdint>

#define D 128
#define RPB 32   // rows per gemm block

// ---- integer degree count --------------------------------------------------
__global__ __launch_bounds__(256) void deg_kernel(const int* __restrict__ src,
    const int* __restrict__ dst, int* __restrict__ dego, int* __restrict__ degi,
    int E) {
  int e = blockIdx.x * 256 + threadIdx.x;
  if (e < E) {
    atomicAdd(dego + src[e], 1);
    atomicAdd(degi + dst[e], 1);
  }
}

// ---- norms from int degrees -------------------------------------------------
__global__ __launch_bounds__(256) void norm_kernel(const int* __restrict__ dego,
    const int* __restrict__ degi, float* __restrict__ ns, float* __restrict__ nd,
    int N) {
  int i = blockIdx.x * 256 + threadIdx.x;
  if (i < N) {
    ns[i] = rsqrtf(fmaxf((float)dego[i], 1.0f));
    nd[i] = rsqrtf(fmaxf((float)degi[i], 1.0f));
  }
}

// ---- hierarchical exclusive scan (3 stages, all wide) -----------------------
__global__ __launch_bounds__(256) void scan1_kernel(const int* __restrict__ deg,
    int* __restrict__ loc, int* __restrict__ bsum, int N) {
  __shared__ int tmp[256];
  int i = blockIdx.x * 256 + threadIdx.x;
  int v = (i < N) ? deg[i] : 0;
  tmp[threadIdx.x] = v;
  __syncthreads();
  #pragma unroll
  for (int off = 1; off < 256; off <<= 1) {
    int t = (threadIdx.x >= off) ? tmp[threadIdx.x - off] : 0;
    __syncthreads();
    tmp[threadIdx.x] += t;
    __syncthreads();
  }
  if (i < N) loc[i] = tmp[threadIdx.x] - v;      // exclusive
  if (threadIdx.x == 255) bsum[blockIdx.x] = tmp[255];
}

__global__ __launch_bounds__(256) void scan2_kernel(int* __restrict__ bsum, int nb) {
  __shared__ int tmp[256];
  int t = threadIdx.x;
  int v = (t < nb) ? bsum[t] : 0;
  tmp[t] = v;
  __syncthreads();
  #pragma unroll
  for (int off = 1; off < 256; off <<= 1) {
    int u = (t >= off) ? tmp[t - off] : 0;
    __syncthreads();
    tmp[t] += u;
    __syncthreads();
  }
  if (t < nb) bsum[t] = tmp[t] - v;              // exclusive block offset
}

__global__ __launch_bounds__(256) void scan3_kernel(const int* __restrict__ loc,
    const int* __restrict__ bsum, int* __restrict__ row_ptr,
    int* __restrict__ cursor, int N, int E) {
  int i = blockIdx.x * 256 + threadIdx.x;
  if (i < N) {
    int v = loc[i] + bsum[blockIdx.x];
    row_ptr[i] = v;
    cursor[i] = v;
  }
  if (i == 0) row_ptr[N] = E;
}

// ---- scatter edges into CSR slots -------------------------------------------
__global__ __launch_bounds__(256) void fill_csr(const int* __restrict__ src,
    const int* __restrict__ dst, int* __restrict__ cursor, int* __restrict__ esrc,
    int E) {
  int e = blockIdx.x * 256 + threadIdx.x;
  if (e < E) {
    int slot = atomicAdd(cursor + dst[e], 1);
    esrc[slot] = src[e];
  }
}

// ---- bf16 helpers -----------------------------------------------------------
__device__ __forceinline__ float blo(unsigned u) {
  return __uint_as_float(u << 16);
}
__device__ __forceinline__ float bhi(unsigned u) {
  return __uint_as_float(u & 0xffff0000u);
}
__device__ __forceinline__ unsigned short f2b(float f) {  // RNE
  unsigned u = __float_as_uint(f);
  return (unsigned short)((u + 0x7fffu + ((u >> 16) & 1u)) >> 16);
}

// ---- register-blocked GEMM: z = (nsrc .* x) @ W, z in bf16 ------------------
__device__ __forceinline__ void fma4(float4& acc, float a, const float4& wv) {
  acc.x += a * wv.x;
  acc.y += a * wv.y;
  acc.z += a * wv.z;
  acc.w += a * wv.w;
}

__global__ __launch_bounds__(256, 2) void gemm_kernel(const float* __restrict__ xin,
    const float* __restrict__ nsrc, const float* __restrict__ W,
    unsigned short* __restrict__ zout, int N) {
  __shared__ float Wl[D * D];       // 64 KB
  __shared__ float Al[RPB * D];     // 16 KB
  float4* Wl4 = (float4*)Wl;
  float4* Al4 = (float4*)Al;
  const float4* W4 = (const float4*)W;
  for (int i = threadIdx.x; i < D * D / 4; i += 256) Wl4[i] = W4[i];
  int row0 = blockIdx.x * RPB;
  for (int i = threadIdx.x; i < RPB * D / 4; i += 256) {
    int r = i >> 5;
    int row = row0 + r;
    float4 zv = {0.f, 0.f, 0.f, 0.f};
    if (row < N) {
      float sc = nsrc[row];
      float4 a = ((const float4*)(xin + (size_t)row * D))[i & 31];
      zv.x = a.x * sc; zv.y = a.y * sc; zv.z = a.z * sc; zv.w = a.w * sc;
    }
    Al4[i] = zv;
  }
  __syncthreads();

  int cg = threadIdx.x & 31;
  int slot = threadIdx.x >> 5;          // rows slot*4 .. slot*4+3
  float4 z4 = {0.f, 0.f, 0.f, 0.f};
  float4 acc0 = z4, acc1 = z4, acc2 = z4, acc3 = z4;
  int abase = slot * 4 * 32;

  #pragma unroll 8
  for (int k = 0; k < D; k += 4) {
    float4 w0 = Wl4[(k + 0) * 32 + cg];
    float4 w1 = Wl4[(k + 1) * 32 + cg];
    float4 w2 = Wl4[(k + 2) * 32 + cg];
    float4 w3 = Wl4[(k + 3) * 32 + cg];
    int k4 = k >> 2;
    float4 a0 = Al4[abase + k4];
    float4 a1 = Al4[abase + 32 + k4];
    float4 a2 = Al4[abase + 64 + k4];
    float4 a3 = Al4[abase + 96 + k4];
    fma4(acc0, a0.x, w0); fma4(acc0, a0.y, w1); fma4(acc0, a0.z, w2); fma4(acc0, a0.w, w3);
    fma4(acc1, a1.x, w0); fma4(acc1, a1.y, w1); fma4(acc1, a1.z, w2); fma4(acc1, a1.w, w3);
    fma4(acc2, a2.x, w0); fma4(acc2, a2.y, w1); fma4(acc2, a2.z, w2); fma4(acc2, a2.w, w3);
    fma4(acc3, a3.x, w0); fma4(acc3, a3.y, w1); fma4(acc3, a3.z, w2); fma4(acc3, a3.w, w3);
  }

  #pragma unroll
  for (int q = 0; q < 4; ++q) {
    float4 o = (q == 0) ? acc0 : (q == 1) ? acc1 : (q == 2) ? acc2 : acc3;
    int row = row0 + slot * 4 + q;
    if (row < N) {
      unsigned lo = (unsigned)f2b(o.x) | ((unsigned)f2b(o.y) << 16);
      unsigned hi = (unsigned)f2b(o.z) | ((unsigned)f2b(o.w) << 16);
      uint2 pk; pk.x = lo; pk.y = hi;
      ((uint2*)zout)[(size_t)row * 32 + cg] = pk;   // 4 bf16 at col cg*4
    }
  }
}

// ---- bf16 CSR gather: x = lrelu(ndst*sum z[s] + b); JK max fused ------------
// 16 lanes per row, 16B (8 bf16) per lane, 4x unrolled edge loop.
__global__ __launch_bounds__(256, 8) void gather_kernel(
    const unsigned short* __restrict__ z, const int* __restrict__ row_ptr,
    const int* __restrict__ esrc, const float* __restrict__ ndst,
    const float* __restrict__ bias, const float* __restrict__ jk_in,
    float* __restrict__ xout, float* __restrict__ jk_out, int N) {
  int t = blockIdx.x * 256 + threadIdx.x;
  int row = t >> 4;
  if (row >= N) return;
  int cg = t & 15;                       // 8 bf16 columns: cg*8 ..
  const uint4* zp = (const uint4*)z;     // row stride = 16 uint4
  int b = row_ptr[row];
  int e = row_ptr[row + 1];
  float a0 = 0.f, a1 = 0.f, a2 = 0.f, a3 = 0.f;
  float a4 = 0.f, a5 = 0.f, a6 = 0.f, a7 = 0.f;
  int j = b;
  for (; j + 3 < e; j += 4) {
    int s0 = esrc[j];
    int s1 = esrc[j + 1];
    int s2 = esrc[j + 2];
    int s3 = esrc[j + 3];
    uint4 v0 = zp[(size_t)s0 * 16 + cg];
    uint4 v1 = zp[(size_t)s1 * 16 + cg];
    uint4 v2 = zp[(size_t)s2 * 16 + cg];
    uint4 v3 = zp[(size_t)s3 * 16 + cg];
    a0 += blo(v0.x); a1 += bhi(v0.x); a2 += blo(v0.y); a3 += bhi(v0.y);
    a4 += blo(v0.z); a5 += bhi(v0.z); a6 += blo(v0.w); a7 += bhi(v0.w);
    a0 += blo(v1.x); a1 += bhi(v1.x); a2 += blo(v1.y); a3 += bhi(v1.y);
    a4 += blo(v1.z); a5 += bhi(v1.z); a6 += blo(v1.w); a7 += bhi(v1.w);
    a0 += blo(v2.x); a1 += bhi(v2.x); a2 += blo(v2.y); a3 += bhi(v2.y);
    a4 += blo(v2.z); a5 += bhi(v2.z); a6 += blo(v2.w); a7 += bhi(v2.w);
    a0 += blo(v3.x); a1 += bhi(v3.x); a2 += blo(v3.y); a3 += bhi(v3.y);
    a4 += blo(v3.z); a5 += bhi(v3.z); a6 += blo(v3.w); a7 += bhi(v3.w);
  }
  for (; j < e; ++j) {
    int s0 = esrc[j];
    uint4 v0 = zp[(size_t)s0 * 16 + cg];
    a0 += blo(v0.x); a1 += bhi(v0.x); a2 += blo(v0.y); a3 += bhi(v0.y);
    a4 += blo(v0.z); a5 += bhi(v0.z); a6 += blo(v0.w); a7 += bhi(v0.w);
  }
  float nd = ndst[row];
  float4 b0 = ((const float4*)bias)[cg * 2];
  float4 b1 = ((const float4*)bias)[cg * 2 + 1];
  float4 o0, o1;
  o0.x = nd * a0 + b0.x; o0.y = nd * a1 + b0.y;
  o0.z = nd * a2 + b0.z; o0.w = nd * a3 + b0.w;
  o1.x = nd * a4 + b1.x; o1.y = nd * a5 + b1.y;
  o1.z = nd * a6 + b1.z; o1.w = nd * a7 + b1.w;
  o0.x = o0.x > 0.f ? o0.x : 0.01f * o0.x;
  o0.y = o0.y > 0.f ? o0.y : 0.01f * o0.y;
  o0.z = o0.z > 0.f ? o0.z : 0.01f * o0.z;
  o0.w = o0.w > 0.f ? o0.w : 0.01f * o0.w;
  o1.x = o1.x > 0.f ? o1.x : 0.01f * o1.x;
  o1.y = o1.y > 0.f ? o1.y : 0.01f * o1.y;
  o1.z = o1.z > 0.f ? o1.z : 0.01f * o1.z;
  o1.w = o1.w > 0.f ? o1.w : 0.01f * o1.w;
  size_t o4 = (size_t)row * 32 + cg * 2;
  ((float4*)xout)[o4] = o0;
  ((float4*)xout)[o4 + 1] = o1;
  float4 m0 = ((const float4*)jk_in)[o4];
  float4 m1 = ((const float4*)jk_in)[o4 + 1];
  m0.x = fmaxf(m0.x, o0.x); m0.y = fmaxf(m0.y, o0.y);
  m0.z = fmaxf(m0.z, o0.z); m0.w = fmaxf(m0.w, o0.w);
  m1.x = fmaxf(m1.x, o1.x); m1.y = fmaxf(m1.y, o1.y);
  m1.z = fmaxf(m1.z, o1.z); m1.w = fmaxf(m1.w, o1.w);
  ((float4*)jk_out)[o4] = m0;
  ((float4*)jk_out)[o4 + 1] = m1;
}

extern "C" void kernel_launch(void* const* d_in, const int* in_sizes, int n_in,
                              void* d_out, int out_size, void* d_ws, size_t ws_size,
                              hipStream_t stream) {
  const float* in_feat = (const float*)d_in[0];
  const float* Ws = (const float*)d_in[1];
  const float* bs = (const float*)d_in[2];
  const int* src = (const int*)d_in[3];
  const int* dst = (const int*)d_in[4];
  int N = in_sizes[0] / D;
  int L = in_sizes[2] / D;
  int E = in_sizes[3];
  float* out = (float*)d_out;

  int nb = (N + 255) / 256;   // scan blocks (must be <= 256)

  // workspace layout
  char* p = (char*)d_ws;
  int* dego    = (int*)p;   p += (size_t)N * 4;      // later: local-scan temp
  int* degi    = (int*)p;   p += (size_t)N * 4;
  int* row_ptr = (int*)p;   p += (size_t)(N + 1) * 4;
  int* cursor  = (int*)p;   p += (size_t)N * 4;
  int* bsum    = (int*)p;   p += 256 * 4;
  int* esrc    = (int*)p;   p += (size_t)E * 4;
  float* nsrc  = (float*)p; p += (size_t)N * 4;
  float* ndst  = (float*)p; p += (size_t)N * 4;
  unsigned short* z = (unsigned short*)p; p += (size_t)N * D * 2;
  float* x     = (float*)p;                           // N*D floats

  hipMemsetAsync(dego, 0, 2 * (size_t)N * 4, stream);
  deg_kernel<<<(E + 255) / 256, 256, 0, stream>>>(src, dst, dego, degi, E);
  norm_kernel<<<(N + 255) / 256, 256, 0, stream>>>(dego, degi, nsrc, ndst, N);
  scan1_kernel<<<nb, 256, 0, stream>>>(degi, dego, bsum, N);
  scan2_kernel<<<1, 256, 0, stream>>>(bsum, nb);
  scan3_kernel<<<nb, 256, 0, stream>>>(dego, bsum, row_ptr, cursor, N, E);
  fill_csr<<<(E + 255) / 256, 256, 0, stream>>>(src, dst, cursor, esrc, E);

  int mb = (N + RPB - 1) / RPB;
  int gb = (int)(((long long)N * 16 + 255) / 256);
  for (int l = 0; l < L; ++l) {
    const float* xin = (l == 0) ? in_feat : x;
    const float* jk_in = (l == 0) ? in_feat : out;   // layer 0 seeds JK max
    gemm_kernel<<<mb, 256, 0, stream>>>(xin, nsrc, Ws + (size_t)l * D * D, z, N);
    gather_kernel<<<gb, 256, 0, stream>>>(z, row_ptr, esrc, ndst,
                                          bs + (size_t)l * D, jk_in, x, out, N);
  }
}

// Round 8
// 377.577 us; speedup vs baseline: 15.9895x; 1.3015x over previous
//
#include <hip/hip_runtime.h>
#include <cstdint>

#define D 128

typedef __attribute__((ext_vector_type(8))) short bf16x8;
typedef __attribute__((ext_vector_type(4))) float f32x4;

// ---- bf16 helpers -----------------------------------------------------------
__device__ __forceinline__ unsigned short f2b(float f) {  // RNE
  unsigned u = __float_as_uint(f);
  return (unsigned short)((u + 0x7fffu + ((u >> 16) & 1u)) >> 16);
}
__device__ __forceinline__ float blo(unsigned u) { return __uint_as_float(u << 16); }
__device__ __forceinline__ float bhi(unsigned u) { return __uint_as_float(u & 0xffff0000u); }

// ---- integer degree count (4 edges/thread) ----------------------------------
__global__ __launch_bounds__(256) void deg_kernel(const int* __restrict__ src,
    const int* __restrict__ dst, int* __restrict__ dego, int* __restrict__ degi,
    int E) {
  int e4 = blockIdx.x * 256 + threadIdx.x;
  int base = e4 * 4;
  if (base + 3 < E) {
    int4 s = ((const int4*)src)[e4];
    int4 d = ((const int4*)dst)[e4];
    atomicAdd(dego + s.x, 1); atomicAdd(dego + s.y, 1);
    atomicAdd(dego + s.z, 1); atomicAdd(dego + s.w, 1);
    atomicAdd(degi + d.x, 1); atomicAdd(degi + d.y, 1);
    atomicAdd(degi + d.z, 1); atomicAdd(degi + d.w, 1);
  } else {
    for (int e = base; e < E; ++e) {
      atomicAdd(dego + src[e], 1);
      atomicAdd(degi + dst[e], 1);
    }
  }
}

// ---- norms from int degrees -------------------------------------------------
__global__ __launch_bounds__(256) void norm_kernel(const int* __restrict__ dego,
    const int* __restrict__ degi, float* __restrict__ ns, float* __restrict__ nd,
    int N) {
  int i = blockIdx.x * 256 + threadIdx.x;
  if (i < N) {
    ns[i] = rsqrtf(fmaxf((float)dego[i], 1.0f));
    nd[i] = rsqrtf(fmaxf((float)degi[i], 1.0f));
  }
}

// ---- hierarchical exclusive scan (3 stages, all wide) -----------------------
__global__ __launch_bounds__(256) void scan1_kernel(const int* __restrict__ deg,
    int* __restrict__ loc, int* __restrict__ bsum, int N) {
  __shared__ int tmp[256];
  int i = blockIdx.x * 256 + threadIdx.x;
  int v = (i < N) ? deg[i] : 0;
  tmp[threadIdx.x] = v;
  __syncthreads();
  #pragma unroll
  for (int off = 1; off < 256; off <<= 1) {
    int t = (threadIdx.x >= off) ? tmp[threadIdx.x - off] : 0;
    __syncthreads();
    tmp[threadIdx.x] += t;
    __syncthreads();
  }
  if (i < N) loc[i] = tmp[threadIdx.x] - v;      // exclusive
  if (threadIdx.x == 255) bsum[blockIdx.x] = tmp[255];
}

__global__ __launch_bounds__(256) void scan2_kernel(int* __restrict__ bsum, int nb) {
  __shared__ int tmp[256];
  int t = threadIdx.x;
  int v = (t < nb) ? bsum[t] : 0;
  tmp[t] = v;
  __syncthreads();
  #pragma unroll
  for (int off = 1; off < 256; off <<= 1) {
    int u = (t >= off) ? tmp[t - off] : 0;
    __syncthreads();
    tmp[t] += u;
    __syncthreads();
  }
  if (t < nb) bsum[t] = tmp[t] - v;              // exclusive block offset
}

__global__ __launch_bounds__(256) void scan3_kernel(const int* __restrict__ loc,
    const int* __restrict__ bsum, int* __restrict__ row_ptr,
    int* __restrict__ cursor, int N, int E) {
  int i = blockIdx.x * 256 + threadIdx.x;
  if (i < N) {
    int v = loc[i] + bsum[blockIdx.x];
    row_ptr[i] = v;
    cursor[i] = v;
  }
  if (i == 0) row_ptr[N] = E;
}

// ---- scatter edges into CSR slots (4 edges/thread) --------------------------
__global__ __launch_bounds__(256) void fill_csr(const int* __restrict__ src,
    const int* __restrict__ dst, int* __restrict__ cursor, int* __restrict__ esrc,
    int E) {
  int e4 = blockIdx.x * 256 + threadIdx.x;
  int base = e4 * 4;
  if (base + 3 < E) {
    int4 s = ((const int4*)src)[e4];
    int4 d = ((const int4*)dst)[e4];
    esrc[atomicAdd(cursor + d.x, 1)] = s.x;
    esrc[atomicAdd(cursor + d.y, 1)] = s.y;
    esrc[atomicAdd(cursor + d.z, 1)] = s.z;
    esrc[atomicAdd(cursor + d.w, 1)] = s.w;
  } else {
    for (int e = base; e < E; ++e) {
      esrc[atomicAdd(cursor + dst[e], 1)] = src[e];
    }
  }
}

// ---- MFMA GEMM: z = nsrc .* (x @ W), z in bf16 ------------------------------
// Block: 256 thr = 4 waves; wave w owns rows [bid*64 + 16w, +16), all 128 cols.
// A (x rows, bf16) loaded from global: lane = row + 16*(k/8), 8 contiguous k.
// B = W staged transposed->bf16 in LDS, XOR-swizzled (col-stride 256B would be
// a 16-way bank conflict otherwise). C/D: col=lane&15, row=(lane>>4)*4+q.
template<bool INF32>
__global__ __launch_bounds__(256, 4) void gemm_mfma(const float* __restrict__ xf,
    const unsigned short* __restrict__ xb, const float* __restrict__ nsrc,
    const float* __restrict__ W, unsigned short* __restrict__ zout, int N) {
  __shared__ unsigned short Wt[D * D];   // 32 KB, Wt[c][k] swizzled
  for (int i = threadIdx.x; i < D * D; i += 256) {
    int k = i >> 7;
    int c = i & 127;
    // swizzle: ushort index ^ ((c&7)<<3)  (== byte ^ ((c&7)<<4))
    Wt[(c * D + k) ^ ((c & 7) << 3)] = f2b(W[i]);   // W[i] = W[k][c], coalesced
  }
  __syncthreads();

  int wave = threadIdx.x >> 6;
  int lane = threadIdx.x & 63;
  int r16 = lane & 15;
  int kgrp = lane >> 4;                  // 0..3
  int rw = blockIdx.x * 64 + wave * 16;  // wave's row base

  f32x4 acc[8] = {};
  int gr = rw + r16;
  if (gr >= N) gr = N - 1;               // clamp; stores are guarded

  #pragma unroll
  for (int ks = 0; ks < 4; ++ks) {
    int k0 = ks * 32 + kgrp * 8;
    bf16x8 a;
    if (INF32) {
      const float4* p = (const float4*)(xf + (size_t)gr * D + k0);
      float4 lo = p[0], hi = p[1];
      a[0] = (short)f2b(lo.x); a[1] = (short)f2b(lo.y);
      a[2] = (short)f2b(lo.z); a[3] = (short)f2b(lo.w);
      a[4] = (short)f2b(hi.x); a[5] = (short)f2b(hi.y);
      a[6] = (short)f2b(hi.z); a[7] = (short)f2b(hi.w);
    } else {
      a = *(const bf16x8*)(xb + (size_t)gr * D + k0);
    }
    #pragma unroll
    for (int ct = 0; ct < 8; ++ct) {
      int c = ct * 16 + r16;
      bf16x8 b = *(const bf16x8*)(Wt + ((c * D + k0) ^ ((c & 7) << 3)));
      acc[ct] = __builtin_amdgcn_mfma_f32_16x16x32_bf16(a, b, acc[ct], 0, 0, 0);
    }
  }

  #pragma unroll
  for (int q = 0; q < 4; ++q) {
    int row = rw + kgrp * 4 + q;
    if (row < N) {
      float ns = nsrc[row];
      #pragma unroll
      for (int ct = 0; ct < 8; ++ct) {
        zout[(size_t)row * D + ct * 16 + r16] = f2b(acc[ct][q] * ns);
      }
    }
  }
}

// ---- bf16 CSR gather: x = lrelu(ndst*sum z[s] + b); JK max; x out as bf16 ---
// 16 lanes per row, 16B (8 bf16) per lane, 4x unrolled edge loop.
__global__ __launch_bounds__(256, 8) void gather_kernel(
    const unsigned short* __restrict__ z, const int* __restrict__ row_ptr,
    const int* __restrict__ esrc, const float* __restrict__ ndst,
    const float* __restrict__ bias, const float* __restrict__ jk_in,
    unsigned short* __restrict__ xb_out, float* __restrict__ jk_out,
    int N, int write_x) {
  int t = blockIdx.x * 256 + threadIdx.x;
  int row = t >> 4;
  if (row >= N) return;
  int cg = t & 15;                       // 8 bf16 columns: cg*8 ..
  const uint4* zp = (const uint4*)z;     // row stride = 16 uint4
  int b = row_ptr[row];
  int e = row_ptr[row + 1];
  float a0 = 0.f, a1 = 0.f, a2 = 0.f, a3 = 0.f;
  float a4 = 0.f, a5 = 0.f, a6 = 0.f, a7 = 0.f;
  int j = b;
  for (; j + 3 < e; j += 4) {
    int s0 = esrc[j];
    int s1 = esrc[j + 1];
    int s2 = esrc[j + 2];
    int s3 = esrc[j + 3];
    uint4 v0 = zp[(size_t)s0 * 16 + cg];
    uint4 v1 = zp[(size_t)s1 * 16 + cg];
    uint4 v2 = zp[(size_t)s2 * 16 + cg];
    uint4 v3 = zp[(size_t)s3 * 16 + cg];
    a0 += blo(v0.x); a1 += bhi(v0.x); a2 += blo(v0.y); a3 += bhi(v0.y);
    a4 += blo(v0.z); a5 += bhi(v0.z); a6 += blo(v0.w); a7 += bhi(v0.w);
    a0 += blo(v1.x); a1 += bhi(v1.x); a2 += blo(v1.y); a3 += bhi(v1.y);
    a4 += blo(v1.z); a5 += bhi(v1.z); a6 += blo(v1.w); a7 += bhi(v1.w);
    a0 += blo(v2.x); a1 += bhi(v2.x); a2 += blo(v2.y); a3 += bhi(v2.y);
    a4 += blo(v2.z); a5 += bhi(v2.z); a6 += blo(v2.w); a7 += bhi(v2.w);
    a0 += blo(v3.x); a1 += bhi(v3.x); a2 += blo(v3.y); a3 += bhi(v3.y);
    a4 += blo(v3.z); a5 += bhi(v3.z); a6 += blo(v3.w); a7 += bhi(v3.w);
  }
  for (; j < e; ++j) {
    int s0 = esrc[j];
    uint4 v0 = zp[(size_t)s0 * 16 + cg];
    a0 += blo(v0.x); a1 += bhi(v0.x); a2 += blo(v0.y); a3 += bhi(v0.y);
    a4 += blo(v0.z); a5 += bhi(v0.z); a6 += blo(v0.w); a7 += bhi(v0.w);
  }
  float nd = ndst[row];
  float4 b0 = ((const float4*)bias)[cg * 2];
  float4 b1 = ((const float4*)bias)[cg * 2 + 1];
  float4 o0, o1;
  o0.x = nd * a0 + b0.x; o0.y = nd * a1 + b0.y;
  o0.z = nd * a2 + b0.z; o0.w = nd * a3 + b0.w;
  o1.x = nd * a4 + b1.x; o1.y = nd * a5 + b1.y;
  o1.z = nd * a6 + b1.z; o1.w = nd * a7 + b1.w;
  o0.x = o0.x > 0.f ? o0.x : 0.01f * o0.x;
  o0.y = o0.y > 0.f ? o0.y : 0.01f * o0.y;
  o0.z = o0.z > 0.f ? o0.z : 0.01f * o0.z;
  o0.w = o0.w > 0.f ? o0.w : 0.01f * o0.w;
  o1.x = o1.x > 0.f ? o1.x : 0.01f * o1.x;
  o1.y = o1.y > 0.f ? o1.y : 0.01f * o1.y;
  o1.z = o1.z > 0.f ? o1.z : 0.01f * o1.z;
  o1.w = o1.w > 0.f ? o1.w : 0.01f * o1.w;
  if (write_x) {
    uint4 px;
    px.x = (unsigned)f2b(o0.x) | ((unsigned)f2b(o0.y) << 16);
    px.y = (unsigned)f2b(o0.z) | ((unsigned)f2b(o0.w) << 16);
    px.z = (unsigned)f2b(o1.x) | ((unsigned)f2b(o1.y) << 16);
    px.w = (unsigned)f2b(o1.z) | ((unsigned)f2b(o1.w) << 16);
    ((uint4*)xb_out)[(size_t)row * 16 + cg] = px;
  }
  size_t o4 = (size_t)row * 32 + cg * 2;
  float4 m0 = ((const float4*)jk_in)[o4];
  float4 m1 = ((const float4*)jk_in)[o4 + 1];
  m0.x = fmaxf(m0.x, o0.x); m0.y = fmaxf(m0.y, o0.y);
  m0.z = fmaxf(m0.z, o0.z); m0.w = fmaxf(m0.w, o0.w);
  m1.x = fmaxf(m1.x, o1.x); m1.y = fmaxf(m1.y, o1.y);
  m1.z = fmaxf(m1.z, o1.z); m1.w = fmaxf(m1.w, o1.w);
  ((float4*)jk_out)[o4] = m0;
  ((float4*)jk_out)[o4 + 1] = m1;
}

extern "C" void kernel_launch(void* const* d_in, const int* in_sizes, int n_in,
                              void* d_out, int out_size, void* d_ws, size_t ws_size,
                              hipStream_t stream) {
  const float* in_feat = (const float*)d_in[0];
  const float* Ws = (const float*)d_in[1];
  const float* bs = (const float*)d_in[2];
  const int* src = (const int*)d_in[3];
  const int* dst = (const int*)d_in[4];
  int N = in_sizes[0] / D;
  int L = in_sizes[2] / D;
  int E = in_sizes[3];
  float* out = (float*)d_out;

  int nb = (N + 255) / 256;   // scan blocks (must be <= 256)

  // workspace layout (keep every段 16B-aligned)
  char* p = (char*)d_ws;
  int* dego    = (int*)p;   p += (size_t)N * 4;      // reused: local-scan temp
  int* degi    = (int*)p;   p += (size_t)N * 4;
  int* row_ptr = (int*)p;   p += (size_t)(N + 4) * 4;
  int* cursor  = (int*)p;   p += (size_t)N * 4;
  int* bsum    = (int*)p;   p += 256 * 4;
  int* esrc    = (int*)p;   p += (((size_t)E + 3) & ~(size_t)3) * 4;
  float* nsrc  = (float*)p; p += (size_t)N * 4;
  float* ndst  = (float*)p; p += (size_t)N * 4;
  unsigned short* z  = (unsigned short*)p; p += (size_t)N * D * 2;
  unsigned short* xb = (unsigned short*)p;           // N*D bf16

  int e4 = (E + 3) / 4;
  hipMemsetAsync(dego, 0, 2 * (size_t)N * 4, stream);
  deg_kernel<<<(e4 + 255) / 256, 256, 0, stream>>>(src, dst, dego, degi, E);
  norm_kernel<<<(N + 255) / 256, 256, 0, stream>>>(dego, degi, nsrc, ndst, N);
  scan1_kernel<<<nb, 256, 0, stream>>>(degi, dego, bsum, N);
  scan2_kernel<<<1, 256, 0, stream>>>(bsum, nb);
  scan3_kernel<<<nb, 256, 0, stream>>>(dego, bsum, row_ptr, cursor, N, E);
  fill_csr<<<(e4 + 255) / 256, 256, 0, stream>>>(src, dst, cursor, esrc, E);

  int mb = (N + 63) / 64;
  int gb = (int)(((long long)N * 16 + 255) / 256);
  for (int l = 0; l < L; ++l) {
    const float* jk_in = (l == 0) ? in_feat : out;   // layer 0 seeds JK max
    if (l == 0) {
      gemm_mfma<true><<<mb, 256, 0, stream>>>(in_feat, nullptr, nsrc,
                                              Ws, z, N);
    } else {
      gemm_mfma<false><<<mb, 256, 0, stream>>>(nullptr, xb, nsrc,
                                               Ws + (size_t)l * D * D, z, N);
    }
    gather_kernel<<<gb, 256, 0, stream>>>(z, row_ptr, esrc, ndst,
                                          bs + (size_t)l * D, jk_in, xb, out,
                                          N, (l + 1 < L) ? 1 : 0);
  }
}